// Round 1
// baseline (1326.006 us; speedup 1.0000x reference)
//
#include <hip/hip_runtime.h>

#define NN 50000
#define NE 600000
#define HD 128
#define NL 4

typedef __bf16 bf16x8 __attribute__((ext_vector_type(8)));
typedef float f32x4 __attribute__((ext_vector_type(4)));

__device__ __forceinline__ unsigned short f2bf(float x){
  union { float f; unsigned int u; } v; v.f = x;
  unsigned int r = v.u + 0x7FFFu + ((v.u >> 16) & 1u);
  return (unsigned short)(r >> 16);
}
__device__ __forceinline__ float silu_f(float x){ return x / (1.f + __expf(-x)); }

__device__ __forceinline__ f32x4 mfma_b16(bf16x8 a, bf16x8 b, f32x4 c){
  return __builtin_amdgcn_mfma_f32_16x16x32_bf16(a, b, c, 0, 0, 0);
}

// pack weight [K x 128] f32 row-major -> MFMA B-fragment order (bf16)
// dst[((kk*8+nb)*64+lane)*8+j] = W[kk*32 + (lane>>4)*8 + j][nb*16 + (lane&15)]
__global__ __launch_bounds__(256) void pack_b(const float* __restrict__ src,
    unsigned short* __restrict__ dst, int K, int srcLayerStride){
  int layer = blockIdx.y;
  int tid = blockIdx.x*256 + threadIdx.x;           // < K*128
  int j = tid & 7, lane = (tid >> 3) & 63, nb = (tid >> 9) & 7, kk = tid >> 12;
  int krow = (kk << 5) + ((lane >> 4) << 3) + j;
  int c = (nb << 4) + (lane & 15);
  dst[(size_t)layer*K*HD + tid] = f2bf(src[(size_t)layer*srcLayerStride + krow*HD + c]);
}

__global__ __launch_bounds__(256) void emb_kernel(
    const float* __restrict__ loc, const float* __restrict__ vel,
    const float* __restrict__ ew, const float* __restrict__ eb,
    float* __restrict__ hf, unsigned short* __restrict__ hb)
{
  int gid = blockIdx.x*256 + threadIdx.x;   // = n*128 + j
  int n = gid >> 7, j = gid & 127;
  float s = eb[j];
  s += loc[n*3+0]*ew[0*HD+j] + loc[n*3+1]*ew[1*HD+j] + loc[n*3+2]*ew[2*HD+j];
  s += vel[n*3+0]*ew[3*HD+j] + vel[n*3+1]*ew[4*HD+j] + vel[n*3+2]*ew[5*HD+j];
  hf[gid] = s;
  hb[gid] = f2bf(s);
}

// ---- edge kernel: m = silu(silu([h_r|h_c|ea] @ W1 + b1) @ W2 + b2); atomicAdd into agg[row] ----
__global__ __launch_bounds__(256) void edge_kernel(
    const unsigned short* __restrict__ hb, const float* __restrict__ ea,
    const int* __restrict__ rowIdx, const int* __restrict__ colIdx,
    const unsigned short* __restrict__ B1p, const unsigned short* __restrict__ B2p,
    const float* __restrict__ bias1, const float* __restrict__ bias2,
    const float* __restrict__ wea, float* __restrict__ agg)
{
  __shared__ alignas(128) char sA[64*512];
  __shared__ alignas(128) char sT[64*256];
  __shared__ int sRow[64];

  const int t = threadIdx.x;
  const int e0 = blockIdx.x << 6;

  { // stage A = [h[row]|h[col]] : 64 edges x 256 bf16, XOR-swizzled 16B chunks
    const int el = t >> 2, p = t & 3;
    int node = (p < 2) ? rowIdx[e0 + el] : colIdx[e0 + el];
    if (p == 0) sRow[el] = node;
    const uint4* src = reinterpret_cast<const uint4*>(hb + (size_t)node*HD + (p & 1)*64);
    #pragma unroll
    for (int c = 0; c < 8; ++c){
      int kb = (p << 7) + (c << 4);
      *reinterpret_cast<uint4*>(sA + (el << 9) + (kb ^ ((el & 7) << 4))) = src[c];
    }
  }
  __syncthreads();

  const int w = t >> 6, l = t & 63;
  const int lw = l >> 4, ll = l & 15;

  f32x4 acc[4][2] = {};
  #pragma unroll
  for (int kk = 0; kk < 8; ++kk){
    bf16x8 a[4], b[2];
    #pragma unroll
    for (int r = 0; r < 4; ++r){
      int row = (r << 4) + ll;
      int kb = (kk << 6) + (lw << 4);
      a[r] = *reinterpret_cast<const bf16x8*>(sA + (row << 9) + (kb ^ ((row & 7) << 4)));
    }
    #pragma unroll
    for (int c = 0; c < 2; ++c)
      b[c] = *reinterpret_cast<const bf16x8*>(B1p + ((((kk << 3) + (w << 1) + c) << 6) + l)*8);
    #pragma unroll
    for (int r = 0; r < 4; ++r)
      #pragma unroll
      for (int c = 0; c < 2; ++c)
        acc[r][c] = mfma_b16(a[r], b[c], acc[r][c]);
  }

  // epilogue 1: + bias + edge_attr rank-2 + SiLU -> sT (bf16, swizzled)
  #pragma unroll
  for (int r = 0; r < 4; ++r){
    #pragma unroll
    for (int i = 0; i < 4; ++i){
      int rt = (r << 4) + (lw << 2) + i;
      float a0 = ea[2*(e0 + rt)], a1 = ea[2*(e0 + rt) + 1];
      #pragma unroll
      for (int c = 0; c < 2; ++c){
        int col = (w << 5) + (c << 4) + ll;
        float v = acc[r][c][i] + bias1[col] + a0*wea[col] + a1*wea[HD + col];
        v = silu_f(v);
        *reinterpret_cast<unsigned short*>(sT + (rt << 8) + ((col << 1) ^ ((rt & 7) << 4))) = f2bf(v);
      }
    }
  }
  __syncthreads();

  f32x4 acc2[4][2] = {};
  #pragma unroll
  for (int kk = 0; kk < 4; ++kk){
    bf16x8 a[4], b[2];
    #pragma unroll
    for (int r = 0; r < 4; ++r){
      int row = (r << 4) + ll;
      int kb = (kk << 6) + (lw << 4);
      a[r] = *reinterpret_cast<const bf16x8*>(sT + (row << 8) + (kb ^ ((row & 7) << 4)));
    }
    #pragma unroll
    for (int c = 0; c < 2; ++c)
      b[c] = *reinterpret_cast<const bf16x8*>(B2p + ((((kk << 3) + (w << 1) + c) << 6) + l)*8);
    #pragma unroll
    for (int r = 0; r < 4; ++r)
      #pragma unroll
      for (int c = 0; c < 2; ++c)
        acc2[r][c] = mfma_b16(a[r], b[c], acc2[r][c]);
  }

  // epilogue 2: + bias + SiLU -> scatter
  #pragma unroll
  for (int r = 0; r < 4; ++r){
    #pragma unroll
    for (int i = 0; i < 4; ++i){
      int rt = (r << 4) + (lw << 2) + i;
      int nrow = sRow[rt];
      #pragma unroll
      for (int c = 0; c < 2; ++c){
        int col = (w << 5) + (c << 4) + ll;
        float v = silu_f(acc2[r][c][i] + bias2[col]);
        atomicAdd(agg + (size_t)nrow*HD + col, v);
      }
    }
  }
}

// ---- node kernel: h += silu([h|agg] @ W1 + b1) @ W2 + b2 ----
__global__ __launch_bounds__(256) void node_kernel(
    unsigned short* hb, const float* __restrict__ agg,
    const unsigned short* __restrict__ B1p, const unsigned short* __restrict__ B2p,
    const float* __restrict__ bias1, const float* __restrict__ bias2,
    float* hf)
{
  __shared__ alignas(128) char sA[64*512];
  __shared__ alignas(128) char sT[64*256];
  const int t = threadIdx.x;
  const int n0 = blockIdx.x << 6;

  {
    const int nl_ = t >> 2, p = t & 3;
    const int n = n0 + nl_;
    const bool valid = (n < NN);
    const int nc = valid ? n : 0;
    if (p < 2){
      const uint4* src = reinterpret_cast<const uint4*>(hb + (size_t)nc*HD + p*64);
      #pragma unroll
      for (int c = 0; c < 8; ++c){
        uint4 d = valid ? src[c] : make_uint4(0,0,0,0);
        int kb = (p << 7) + (c << 4);
        *reinterpret_cast<uint4*>(sA + (nl_ << 9) + (kb ^ ((nl_ & 7) << 4))) = d;
      }
    } else {
      const float4* src = reinterpret_cast<const float4*>(agg + (size_t)nc*HD + (p - 2)*64);
      #pragma unroll
      for (int c = 0; c < 8; ++c){
        float4 f0 = make_float4(0.f,0.f,0.f,0.f), f1 = f0;
        if (valid){ f0 = src[2*c]; f1 = src[2*c + 1]; }
        uint4 d;
        d.x = (unsigned)f2bf(f0.x) | ((unsigned)f2bf(f0.y) << 16);
        d.y = (unsigned)f2bf(f0.z) | ((unsigned)f2bf(f0.w) << 16);
        d.z = (unsigned)f2bf(f1.x) | ((unsigned)f2bf(f1.y) << 16);
        d.w = (unsigned)f2bf(f1.z) | ((unsigned)f2bf(f1.w) << 16);
        int kb = (p << 7) + (c << 4);
        *reinterpret_cast<uint4*>(sA + (nl_ << 9) + (kb ^ ((nl_ & 7) << 4))) = d;
      }
    }
  }
  __syncthreads();

  const int w = t >> 6, l = t & 63;
  const int lw = l >> 4, ll = l & 15;

  f32x4 acc[4][2] = {};
  #pragma unroll
  for (int kk = 0; kk < 8; ++kk){
    bf16x8 a[4], b[2];
    #pragma unroll
    for (int r = 0; r < 4; ++r){
      int row = (r << 4) + ll;
      int kb = (kk << 6) + (lw << 4);
      a[r] = *reinterpret_cast<const bf16x8*>(sA + (row << 9) + (kb ^ ((row & 7) << 4)));
    }
    #pragma unroll
    for (int c = 0; c < 2; ++c)
      b[c] = *reinterpret_cast<const bf16x8*>(B1p + ((((kk << 3) + (w << 1) + c) << 6) + l)*8);
    #pragma unroll
    for (int r = 0; r < 4; ++r)
      #pragma unroll
      for (int c = 0; c < 2; ++c)
        acc[r][c] = mfma_b16(a[r], b[c], acc[r][c]);
  }

  #pragma unroll
  for (int r = 0; r < 4; ++r){
    #pragma unroll
    for (int i = 0; i < 4; ++i){
      int rt = (r << 4) + (lw << 2) + i;
      #pragma unroll
      for (int c = 0; c < 2; ++c){
        int col = (w << 5) + (c << 4) + ll;
        float v = silu_f(acc[r][c][i] + bias1[col]);
        *reinterpret_cast<unsigned short*>(sT + (rt << 8) + ((col << 1) ^ ((rt & 7) << 4))) = f2bf(v);
      }
    }
  }
  __syncthreads();

  f32x4 acc2[4][2] = {};
  #pragma unroll
  for (int kk = 0; kk < 4; ++kk){
    bf16x8 a[4], b[2];
    #pragma unroll
    for (int r = 0; r < 4; ++r){
      int row = (r << 4) + ll;
      int kb = (kk << 6) + (lw << 4);
      a[r] = *reinterpret_cast<const bf16x8*>(sT + (row << 8) + (kb ^ ((row & 7) << 4)));
    }
    #pragma unroll
    for (int c = 0; c < 2; ++c)
      b[c] = *reinterpret_cast<const bf16x8*>(B2p + ((((kk << 3) + (w << 1) + c) << 6) + l)*8);
    #pragma unroll
    for (int r = 0; r < 4; ++r)
      #pragma unroll
      for (int c = 0; c < 2; ++c)
        acc2[r][c] = mfma_b16(a[r], b[c], acc2[r][c]);
  }

  #pragma unroll
  for (int r = 0; r < 4; ++r){
    #pragma unroll
    for (int i = 0; i < 4; ++i){
      int rt = (r << 4) + (lw << 2) + i;
      int n = n0 + rt;
      if (n < NN){
        #pragma unroll
        for (int c = 0; c < 2; ++c){
          int col = (w << 5) + (c << 4) + ll;
          float hn = hf[(size_t)n*HD + col] + acc2[r][c][i] + bias2[col];
          hf[(size_t)n*HD + col] = hn;
          hb[(size_t)n*HD + col] = f2bf(hn);
        }
      }
    }
  }
}

// ---- decoder: out = silu(h @ dw1 + db1) @ dw2 + db2 ----
__global__ __launch_bounds__(256) void dec_kernel(
    const unsigned short* __restrict__ hb, const unsigned short* __restrict__ D1p,
    const float* __restrict__ db1, const float* __restrict__ dw2,
    const float* __restrict__ db2, float* __restrict__ outp)
{
  __shared__ alignas(128) char sA[64*256];
  __shared__ float sT[64*133];
  const int t = threadIdx.x;
  const int n0 = blockIdx.x << 6;
  {
    const int nl_ = t >> 2, p = t & 3;
    const int n = n0 + nl_;
    const bool valid = (n < NN);
    const int nc = valid ? n : 0;
    const uint4* src = reinterpret_cast<const uint4*>(hb + (size_t)nc*HD);
    #pragma unroll
    for (int c = 0; c < 4; ++c){
      uint4 d = valid ? src[p*4 + c] : make_uint4(0,0,0,0);
      int kb = (p << 6) + (c << 4);
      *reinterpret_cast<uint4*>(sA + (nl_ << 8) + (kb ^ ((nl_ & 7) << 4))) = d;
    }
  }
  __syncthreads();

  const int w = t >> 6, l = t & 63;
  const int lw = l >> 4, ll = l & 15;

  f32x4 acc[4][2] = {};
  #pragma unroll
  for (int kk = 0; kk < 4; ++kk){
    bf16x8 a[4], b[2];
    #pragma unroll
    for (int r = 0; r < 4; ++r){
      int row = (r << 4) + ll;
      int kb = (kk << 6) + (lw << 4);
      a[r] = *reinterpret_cast<const bf16x8*>(sA + (row << 8) + (kb ^ ((row & 7) << 4)));
    }
    #pragma unroll
    for (int c = 0; c < 2; ++c)
      b[c] = *reinterpret_cast<const bf16x8*>(D1p + ((((kk << 3) + (w << 1) + c) << 6) + l)*8);
    #pragma unroll
    for (int r = 0; r < 4; ++r)
      #pragma unroll
      for (int c = 0; c < 2; ++c)
        acc[r][c] = mfma_b16(a[r], b[c], acc[r][c]);
  }
  #pragma unroll
  for (int r = 0; r < 4; ++r){
    #pragma unroll
    for (int i = 0; i < 4; ++i){
      int rt = (r << 4) + (lw << 2) + i;
      #pragma unroll
      for (int c = 0; c < 2; ++c){
        int col = (w << 5) + (c << 4) + ll;
        sT[rt*133 + col] = silu_f(acc[r][c][i] + db1[col]);
      }
    }
  }
  __syncthreads();
  if (t < 192){
    int rr = t & 63, cc = t >> 6;
    int n = n0 + rr;
    if (n < NN){
      float s = db2[cc];
      #pragma unroll 8
      for (int k = 0; k < HD; ++k) s += sT[rr*133 + k]*dw2[k*3 + cc];
      outp[(size_t)n*3 + cc] = s;
    }
  }
}

extern "C" void kernel_launch(void* const* d_in, const int* in_sizes, int n_in,
                              void* d_out, int out_size, void* d_ws, size_t ws_size,
                              hipStream_t stream)
{
  const float* loc  = (const float*)d_in[0];
  const float* vel  = (const float*)d_in[1];
  const float* ea   = (const float*)d_in[2];
  const int*   row  = (const int*)d_in[3];
  const int*   col  = (const int*)d_in[4];
  const float* embw = (const float*)d_in[5];
  const float* embb = (const float*)d_in[6];
  const float* ew1  = (const float*)d_in[7];
  const float* eb1  = (const float*)d_in[8];
  const float* ew2  = (const float*)d_in[9];
  const float* eb2  = (const float*)d_in[10];
  const float* nw1  = (const float*)d_in[11];
  const float* nb1  = (const float*)d_in[12];
  const float* nw2  = (const float*)d_in[13];
  const float* nb2  = (const float*)d_in[14];
  const float* dw1  = (const float*)d_in[15];
  const float* db1  = (const float*)d_in[16];
  const float* dw2  = (const float*)d_in[17];
  const float* db2  = (const float*)d_in[18];

  char* p = (char*)d_ws;
  float* hf = (float*)p;                       p += (size_t)NN*HD*4;
  unsigned short* hbuf = (unsigned short*)p;   p += (size_t)NN*HD*2;
  float* agg = (float*)p;                      p += (size_t)NN*HD*4;
  unsigned short* ew1p = (unsigned short*)p;   p += (size_t)NL*256*HD*2;
  unsigned short* ew2p = (unsigned short*)p;   p += (size_t)NL*128*HD*2;
  unsigned short* nw1p = (unsigned short*)p;   p += (size_t)NL*256*HD*2;
  unsigned short* nw2p = (unsigned short*)p;   p += (size_t)NL*128*HD*2;
  unsigned short* dw1p = (unsigned short*)p;   p += (size_t)128*HD*2;

  pack_b<<<dim3(128, NL), 256, 0, stream>>>(ew1, ew1p, 256, 258*HD);
  pack_b<<<dim3(64,  NL), 256, 0, stream>>>(ew2, ew2p, 128, 128*HD);
  pack_b<<<dim3(128, NL), 256, 0, stream>>>(nw1, nw1p, 256, 256*HD);
  pack_b<<<dim3(64,  NL), 256, 0, stream>>>(nw2, nw2p, 128, 128*HD);
  pack_b<<<dim3(64,  1 ), 256, 0, stream>>>(dw1, dw1p, 128, 0);

  emb_kernel<<<(NN*HD)/256, 256, 0, stream>>>(loc, vel, embw, embb, hf, hbuf);

  for (int i = 0; i < NL; ++i){
    hipMemsetAsync(agg, 0, (size_t)NN*HD*4, stream);
    edge_kernel<<<NE/64, 256, 0, stream>>>(hbuf, ea, row, col,
        ew1p + (size_t)i*256*HD, ew2p + (size_t)i*128*HD,
        eb1 + i*HD, eb2 + i*HD,
        ew1 + (size_t)i*258*HD + 256*HD, agg);
    node_kernel<<<(NN + 63)/64, 256, 0, stream>>>(hbuf, agg,
        nw1p + (size_t)i*256*HD, nw2p + (size_t)i*128*HD,
        nb1 + i*HD, nb2 + i*HD, hf);
  }

  dec_kernel<<<(NN + 63)/64, 256, 0, stream>>>(hbuf, dw1p, db1, dw2, db2, (float*)d_out);
}

// Round 2
// 1042.921 us; speedup vs baseline: 1.2714x; 1.2714x over previous
//
#include <hip/hip_runtime.h>

#define NN 50000
#define NE 600000
#define HD 128
#define NL 4

typedef __bf16 bf16x8 __attribute__((ext_vector_type(8)));
typedef float f32x4 __attribute__((ext_vector_type(4)));

__device__ __forceinline__ unsigned short f2bf(float x){
  union { float f; unsigned int u; } v; v.f = x;
  unsigned int r = v.u + 0x7FFFu + ((v.u >> 16) & 1u);
  return (unsigned short)(r >> 16);
}
__device__ __forceinline__ float bflo(unsigned u){ union{unsigned u; float f;} v; v.u = u << 16; return v.f; }
__device__ __forceinline__ float bfhi(unsigned u){ union{unsigned u; float f;} v; v.u = u & 0xffff0000u; return v.f; }
__device__ __forceinline__ float silu_f(float x){ return x / (1.f + __expf(-x)); }

__device__ __forceinline__ f32x4 mfma_b16(bf16x8 a, bf16x8 b, f32x4 c){
  return __builtin_amdgcn_mfma_f32_16x16x32_bf16(a, b, c, 0, 0, 0);
}

// pack weight [K x 128] f32 row-major -> MFMA B-fragment order (bf16)
__global__ __launch_bounds__(256) void pack_b(const float* __restrict__ src,
    unsigned short* __restrict__ dst, int K, int srcLayerStride){
  int layer = blockIdx.y;
  int tid = blockIdx.x*256 + threadIdx.x;           // < K*128
  int j = tid & 7, lane = (tid >> 3) & 63, nb = (tid >> 9) & 7, kk = tid >> 12;
  int krow = (kk << 5) + ((lane >> 4) << 3) + j;
  int c = (nb << 4) + (lane & 15);
  dst[(size_t)layer*K*HD + tid] = f2bf(src[(size_t)layer*srcLayerStride + krow*HD + c]);
}

__global__ __launch_bounds__(256) void emb_kernel(
    const float* __restrict__ loc, const float* __restrict__ vel,
    const float* __restrict__ ew, const float* __restrict__ eb,
    float* __restrict__ hf, unsigned short* __restrict__ hb)
{
  int gid = blockIdx.x*256 + threadIdx.x;   // = n*128 + j
  int n = gid >> 7, j = gid & 127;
  float s = eb[j];
  s += loc[n*3+0]*ew[0*HD+j] + loc[n*3+1]*ew[1*HD+j] + loc[n*3+2]*ew[2*HD+j];
  s += vel[n*3+0]*ew[3*HD+j] + vel[n*3+1]*ew[4*HD+j] + vel[n*3+2]*ew[5*HD+j];
  hf[gid] = s;
  hb[gid] = f2bf(s);
}

// ---- CSR build ----
__global__ __launch_bounds__(256) void count_kernel(const int* __restrict__ rowIdx, int* __restrict__ cnt){
  int e = blockIdx.x*256 + threadIdx.x;
  if (e < NE) atomicAdd(cnt + rowIdx[e], 1);
}

__global__ __launch_bounds__(1024) void scan_kernel(const int* __restrict__ cnt,
    int* __restrict__ off, int* __restrict__ cur){
  __shared__ int part[1024];
  const int t = threadIdx.x;
  const int CH = (NN + 1023)/1024;
  const int base = t*CH;
  int s = 0;
  for (int i = 0; i < CH; ++i){
    int idx = base + i;
    if (idx < NN) s += cnt[idx];
  }
  part[t] = s;
  __syncthreads();
  for (int d = 1; d < 1024; d <<= 1){
    int v = (t >= d) ? part[t-d] : 0;
    __syncthreads();
    part[t] += v;
    __syncthreads();
  }
  int run = (t == 0) ? 0 : part[t-1];
  for (int i = 0; i < CH; ++i){
    int idx = base + i;
    if (idx < NN){
      off[idx] = run; cur[idx] = run;
      run += cnt[idx];
    }
  }
  if (t == 0) off[NN] = part[1023];
}

__global__ __launch_bounds__(256) void assign_kernel(
    const int* __restrict__ rowIdx, const int* __restrict__ colIdx,
    const float* __restrict__ ea, int* __restrict__ cur,
    int* __restrict__ row_s, int* __restrict__ col_s, float* __restrict__ ea_s){
  int e = blockIdx.x*256 + threadIdx.x;
  if (e < NE){
    int r = rowIdx[e];
    int s = atomicAdd(cur + r, 1);
    row_s[s] = r;
    col_s[s] = colIdx[e];
    ea_s[2*s]   = ea[2*e];
    ea_s[2*s+1] = ea[2*e+1];
  }
}

// ---- edge kernel (row-sorted): m = silu(silu([h_r|h_c|ea]W1+b1)W2+b2) -> msg (contiguous) ----
__global__ __launch_bounds__(256) void edge_kernel(
    const unsigned short* __restrict__ hb,
    const int* __restrict__ row_s, const int* __restrict__ col_s,
    const float* __restrict__ ea_s,
    const unsigned short* __restrict__ B1p, const unsigned short* __restrict__ B2p,
    const float* __restrict__ bias1, const float* __restrict__ bias2,
    const float* __restrict__ wea, unsigned short* __restrict__ msg)
{
  __shared__ alignas(128) char sA[64*512];   // sT aliased onto first 16KB
  char* sT = sA;

  const int t = threadIdx.x;
  const int e0 = blockIdx.x << 6;

  { // stage A = [h[row]|h[col]] : 64 edges x 256 bf16, XOR-swizzled 16B chunks
    const int el = t >> 2, p = t & 3;
    const int node = (p < 2) ? row_s[e0 + el] : col_s[e0 + el];
    const uint4* src = reinterpret_cast<const uint4*>(hb + (size_t)node*HD + (p & 1)*64);
    #pragma unroll
    for (int c = 0; c < 8; ++c){
      int kb = (p << 7) + (c << 4);
      *reinterpret_cast<uint4*>(sA + (el << 9) + (kb ^ ((el & 7) << 4))) = src[c];
    }
  }
  __syncthreads();

  const int w = t >> 6, l = t & 63;
  const int lw = l >> 4, ll = l & 15;

  f32x4 acc[4][2] = {};
  #pragma unroll
  for (int kk = 0; kk < 8; ++kk){
    bf16x8 a[4], b[2];
    #pragma unroll
    for (int r = 0; r < 4; ++r){
      int row = (r << 4) + ll;
      int kb = (kk << 6) + (lw << 4);
      a[r] = *reinterpret_cast<const bf16x8*>(sA + (row << 9) + (kb ^ ((row & 7) << 4)));
    }
    #pragma unroll
    for (int c = 0; c < 2; ++c)
      b[c] = *reinterpret_cast<const bf16x8*>(B1p + ((((kk << 3) + (w << 1) + c) << 6) + l)*8);
    #pragma unroll
    for (int r = 0; r < 4; ++r)
      #pragma unroll
      for (int c = 0; c < 2; ++c)
        acc[r][c] = mfma_b16(a[r], b[c], acc[r][c]);
  }
  __syncthreads();   // all sA reads done before sT (aliased) is written

  // epilogue 1: + bias + edge_attr rank-2 + SiLU -> sT (bf16, swizzled)
  #pragma unroll
  for (int r = 0; r < 4; ++r){
    #pragma unroll
    for (int i = 0; i < 4; ++i){
      int rt = (r << 4) + (lw << 2) + i;
      float a0 = ea_s[2*(e0 + rt)], a1 = ea_s[2*(e0 + rt) + 1];
      #pragma unroll
      for (int c = 0; c < 2; ++c){
        int col = (w << 5) + (c << 4) + ll;
        float v = acc[r][c][i] + bias1[col] + a0*wea[col] + a1*wea[HD + col];
        v = silu_f(v);
        *reinterpret_cast<unsigned short*>(sT + (rt << 8) + ((col << 1) ^ ((rt & 7) << 4))) = f2bf(v);
      }
    }
  }
  __syncthreads();

  f32x4 acc2[4][2] = {};
  #pragma unroll
  for (int kk = 0; kk < 4; ++kk){
    bf16x8 a[4], b[2];
    #pragma unroll
    for (int r = 0; r < 4; ++r){
      int row = (r << 4) + ll;
      int kb = (kk << 6) + (lw << 4);
      a[r] = *reinterpret_cast<const bf16x8*>(sT + (row << 8) + (kb ^ ((row & 7) << 4)));
    }
    #pragma unroll
    for (int c = 0; c < 2; ++c)
      b[c] = *reinterpret_cast<const bf16x8*>(B2p + ((((kk << 3) + (w << 1) + c) << 6) + l)*8);
    #pragma unroll
    for (int r = 0; r < 4; ++r)
      #pragma unroll
      for (int c = 0; c < 2; ++c)
        acc2[r][c] = mfma_b16(a[r], b[c], acc2[r][c]);
  }
  __syncthreads();   // all sT reads done before rewrite

  // epilogue 2: + bias + SiLU -> sT (bf16, swizzled)
  #pragma unroll
  for (int r = 0; r < 4; ++r){
    #pragma unroll
    for (int i = 0; i < 4; ++i){
      int rt = (r << 4) + (lw << 2) + i;
      #pragma unroll
      for (int c = 0; c < 2; ++c){
        int col = (w << 5) + (c << 4) + ll;
        float v = silu_f(acc2[r][c][i] + bias2[col]);
        *reinterpret_cast<unsigned short*>(sT + (rt << 8) + ((col << 1) ^ ((rt & 7) << 4))) = f2bf(v);
      }
    }
  }
  __syncthreads();

  // copy out: 64 rows x 256B = 16KB fully coalesced at msg + e0*128
  uint4* dst = reinterpret_cast<uint4*>(msg + (size_t)e0*HD);
  #pragma unroll
  for (int it = 0; it < 4; ++it){
    int g = (it << 12) + (t << 4);
    int row = g >> 8, kb = g & 255;
    dst[g >> 4] = *reinterpret_cast<const uint4*>(sT + (row << 8) + (kb ^ ((row & 7) << 4)));
  }
}

// ---- aggregation: aggb[n] = sum of msg rows in [off[n], off[n+1]) (f32 accum, bf16 out) ----
__global__ __launch_bounds__(256) void agg_kernel(
    const unsigned int* __restrict__ msg32, const int* __restrict__ off,
    unsigned int* __restrict__ aggb32)
{
  const int t = threadIdx.x;
  const int w = t >> 6, lane = t & 63;
  const int n = (blockIdx.x << 2) + w;
  if (n >= NN) return;
  const int j0 = off[n], j1 = off[n+1];
  float a0 = 0.f, a1 = 0.f;
  int j = j0;
  for (; j + 1 < j1; j += 2){
    unsigned u0 = msg32[(size_t)j*64 + lane];
    unsigned u1 = msg32[(size_t)(j+1)*64 + lane];
    a0 += bflo(u0) + bflo(u1);
    a1 += bfhi(u0) + bfhi(u1);
  }
  if (j < j1){
    unsigned u0 = msg32[(size_t)j*64 + lane];
    a0 += bflo(u0);
    a1 += bfhi(u0);
  }
  aggb32[(size_t)n*64 + lane] = (unsigned)f2bf(a0) | ((unsigned)f2bf(a1) << 16);
}

// ---- node kernel: h += silu([h|agg] @ W1 + b1) @ W2 + b2 ----
__global__ __launch_bounds__(256) void node_kernel(
    unsigned short* hb, const unsigned short* __restrict__ aggb,
    const unsigned short* __restrict__ B1p, const unsigned short* __restrict__ B2p,
    const float* __restrict__ bias1, const float* __restrict__ bias2,
    float* hf)
{
  __shared__ alignas(128) char sA[64*512];
  char* sT = sA;
  const int t = threadIdx.x;
  const int n0 = blockIdx.x << 6;

  {
    const int nl_ = t >> 2, p = t & 3;
    const int n = n0 + nl_;
    const bool valid = (n < NN);
    const int nc = valid ? n : 0;
    const unsigned short* basep = (p < 2) ? hb : aggb;
    const uint4* src = reinterpret_cast<const uint4*>(basep + (size_t)nc*HD + (p & 1)*64);
    #pragma unroll
    for (int c = 0; c < 8; ++c){
      uint4 d = valid ? src[c] : make_uint4(0,0,0,0);
      int kb = (p << 7) + (c << 4);
      *reinterpret_cast<uint4*>(sA + (nl_ << 9) + (kb ^ ((nl_ & 7) << 4))) = d;
    }
  }
  __syncthreads();

  const int w = t >> 6, l = t & 63;
  const int lw = l >> 4, ll = l & 15;

  f32x4 acc[4][2] = {};
  #pragma unroll
  for (int kk = 0; kk < 8; ++kk){
    bf16x8 a[4], b[2];
    #pragma unroll
    for (int r = 0; r < 4; ++r){
      int row = (r << 4) + ll;
      int kb = (kk << 6) + (lw << 4);
      a[r] = *reinterpret_cast<const bf16x8*>(sA + (row << 9) + (kb ^ ((row & 7) << 4)));
    }
    #pragma unroll
    for (int c = 0; c < 2; ++c)
      b[c] = *reinterpret_cast<const bf16x8*>(B1p + ((((kk << 3) + (w << 1) + c) << 6) + l)*8);
    #pragma unroll
    for (int r = 0; r < 4; ++r)
      #pragma unroll
      for (int c = 0; c < 2; ++c)
        acc[r][c] = mfma_b16(a[r], b[c], acc[r][c]);
  }
  __syncthreads();

  #pragma unroll
  for (int r = 0; r < 4; ++r){
    #pragma unroll
    for (int i = 0; i < 4; ++i){
      int rt = (r << 4) + (lw << 2) + i;
      #pragma unroll
      for (int c = 0; c < 2; ++c){
        int col = (w << 5) + (c << 4) + ll;
        float v = silu_f(acc[r][c][i] + bias1[col]);
        *reinterpret_cast<unsigned short*>(sT + (rt << 8) + ((col << 1) ^ ((rt & 7) << 4))) = f2bf(v);
      }
    }
  }
  __syncthreads();

  f32x4 acc2[4][2] = {};
  #pragma unroll
  for (int kk = 0; kk < 4; ++kk){
    bf16x8 a[4], b[2];
    #pragma unroll
    for (int r = 0; r < 4; ++r){
      int row = (r << 4) + ll;
      int kb = (kk << 6) + (lw << 4);
      a[r] = *reinterpret_cast<const bf16x8*>(sT + (row << 8) + (kb ^ ((row & 7) << 4)));
    }
    #pragma unroll
    for (int c = 0; c < 2; ++c)
      b[c] = *reinterpret_cast<const bf16x8*>(B2p + ((((kk << 3) + (w << 1) + c) << 6) + l)*8);
    #pragma unroll
    for (int r = 0; r < 4; ++r)
      #pragma unroll
      for (int c = 0; c < 2; ++c)
        acc2[r][c] = mfma_b16(a[r], b[c], acc2[r][c]);
  }

  #pragma unroll
  for (int r = 0; r < 4; ++r){
    #pragma unroll
    for (int i = 0; i < 4; ++i){
      int rt = (r << 4) + (lw << 2) + i;
      int n = n0 + rt;
      if (n < NN){
        #pragma unroll
        for (int c = 0; c < 2; ++c){
          int col = (w << 5) + (c << 4) + ll;
          float hn = hf[(size_t)n*HD + col] + acc2[r][c][i] + bias2[col];
          hf[(size_t)n*HD + col] = hn;
          hb[(size_t)n*HD + col] = f2bf(hn);
        }
      }
    }
  }
}

// ---- decoder: out = silu(h @ dw1 + db1) @ dw2 + db2 ----
__global__ __launch_bounds__(256) void dec_kernel(
    const unsigned short* __restrict__ hb, const unsigned short* __restrict__ D1p,
    const float* __restrict__ db1, const float* __restrict__ dw2,
    const float* __restrict__ db2, float* __restrict__ outp)
{
  __shared__ alignas(128) char sA[64*256];
  __shared__ float sT[64*133];
  const int t = threadIdx.x;
  const int n0 = blockIdx.x << 6;
  {
    const int nl_ = t >> 2, p = t & 3;
    const int n = n0 + nl_;
    const bool valid = (n < NN);
    const int nc = valid ? n : 0;
    const uint4* src = reinterpret_cast<const uint4*>(hb + (size_t)nc*HD);
    #pragma unroll
    for (int c = 0; c < 4; ++c){
      uint4 d = valid ? src[p*4 + c] : make_uint4(0,0,0,0);
      int kb = (p << 6) + (c << 4);
      *reinterpret_cast<uint4*>(sA + (nl_ << 8) + (kb ^ ((nl_ & 7) << 4))) = d;
    }
  }
  __syncthreads();

  const int w = t >> 6, l = t & 63;
  const int lw = l >> 4, ll = l & 15;

  f32x4 acc[4][2] = {};
  #pragma unroll
  for (int kk = 0; kk < 4; ++kk){
    bf16x8 a[4], b[2];
    #pragma unroll
    for (int r = 0; r < 4; ++r){
      int row = (r << 4) + ll;
      int kb = (kk << 6) + (lw << 4);
      a[r] = *reinterpret_cast<const bf16x8*>(sA + (row << 8) + (kb ^ ((row & 7) << 4)));
    }
    #pragma unroll
    for (int c = 0; c < 2; ++c)
      b[c] = *reinterpret_cast<const bf16x8*>(D1p + ((((kk << 3) + (w << 1) + c) << 6) + l)*8);
    #pragma unroll
    for (int r = 0; r < 4; ++r)
      #pragma unroll
      for (int c = 0; c < 2; ++c)
        acc[r][c] = mfma_b16(a[r], b[c], acc[r][c]);
  }
  #pragma unroll
  for (int r = 0; r < 4; ++r){
    #pragma unroll
    for (int i = 0; i < 4; ++i){
      int rt = (r << 4) + (lw << 2) + i;
      #pragma unroll
      for (int c = 0; c < 2; ++c){
        int col = (w << 5) + (c << 4) + ll;
        sT[rt*133 + col] = silu_f(acc[r][c][i] + db1[col]);
      }
    }
  }
  __syncthreads();
  if (t < 192){
    int rr = t & 63, cc = t >> 6;
    int n = n0 + rr;
    if (n < NN){
      float s = db2[cc];
      #pragma unroll 8
      for (int k = 0; k < HD; ++k) s += sT[rr*133 + k]*dw2[k*3 + cc];
      outp[(size_t)n*3 + cc] = s;
    }
  }
}

static inline char* alignup(char* p, size_t a){ return (char*)(((uintptr_t)p + a - 1) & ~(a - 1)); }

extern "C" void kernel_launch(void* const* d_in, const int* in_sizes, int n_in,
                              void* d_out, int out_size, void* d_ws, size_t ws_size,
                              hipStream_t stream)
{
  const float* loc  = (const float*)d_in[0];
  const float* vel  = (const float*)d_in[1];
  const float* ea   = (const float*)d_in[2];
  const int*   row  = (const int*)d_in[3];
  const int*   col  = (const int*)d_in[4];
  const float* embw = (const float*)d_in[5];
  const float* embb = (const float*)d_in[6];
  const float* ew1  = (const float*)d_in[7];
  const float* eb1  = (const float*)d_in[8];
  const float* ew2  = (const float*)d_in[9];
  const float* eb2  = (const float*)d_in[10];
  const float* nw1  = (const float*)d_in[11];
  const float* nb1  = (const float*)d_in[12];
  const float* nw2  = (const float*)d_in[13];
  const float* nb2  = (const float*)d_in[14];
  const float* dw1  = (const float*)d_in[15];
  const float* db1  = (const float*)d_in[16];
  const float* dw2  = (const float*)d_in[17];
  const float* db2  = (const float*)d_in[18];

  char* p = (char*)d_ws;
  float* hf = (float*)p;                       p += (size_t)NN*HD*4;
  unsigned short* hbuf = (unsigned short*)p;   p += (size_t)NN*HD*2;
  unsigned short* aggb = (unsigned short*)p;   p += (size_t)NN*HD*2;
  unsigned short* msg = (unsigned short*)p;    p += (size_t)NE*HD*2;
  int* cnt = (int*)p;                          p += (size_t)NN*4;
  int* off = (int*)p;                          p += (size_t)(NN+1)*4;   p = alignup(p, 256);
  int* cur = (int*)p;                          p += (size_t)NN*4;
  int* row_s = (int*)p;                        p += (size_t)NE*4;
  int* col_s = (int*)p;                        p += (size_t)NE*4;
  float* ea_s = (float*)p;                     p += (size_t)NE*2*4;
  unsigned short* ew1p = (unsigned short*)p;   p += (size_t)NL*256*HD*2;
  unsigned short* ew2p = (unsigned short*)p;   p += (size_t)NL*128*HD*2;
  unsigned short* nw1p = (unsigned short*)p;   p += (size_t)NL*256*HD*2;
  unsigned short* nw2p = (unsigned short*)p;   p += (size_t)NL*128*HD*2;
  unsigned short* dw1p = (unsigned short*)p;   p += (size_t)128*HD*2;

  // CSR build (once; row/col/ea don't change across layers)
  hipMemsetAsync(cnt, 0, (size_t)NN*4, stream);
  count_kernel<<<(NE + 255)/256, 256, 0, stream>>>(row, cnt);
  scan_kernel<<<1, 1024, 0, stream>>>(cnt, off, cur);
  assign_kernel<<<(NE + 255)/256, 256, 0, stream>>>(row, col, ea, cur, row_s, col_s, ea_s);

  pack_b<<<dim3(128, NL), 256, 0, stream>>>(ew1, ew1p, 256, 258*HD);
  pack_b<<<dim3(64,  NL), 256, 0, stream>>>(ew2, ew2p, 128, 128*HD);
  pack_b<<<dim3(128, NL), 256, 0, stream>>>(nw1, nw1p, 256, 256*HD);
  pack_b<<<dim3(64,  NL), 256, 0, stream>>>(nw2, nw2p, 128, 128*HD);
  pack_b<<<dim3(64,  1 ), 256, 0, stream>>>(dw1, dw1p, 128, 0);

  emb_kernel<<<(NN*HD)/256, 256, 0, stream>>>(loc, vel, embw, embb, hf, hbuf);

  for (int i = 0; i < NL; ++i){
    edge_kernel<<<NE/64, 256, 0, stream>>>(hbuf, row_s, col_s, ea_s,
        ew1p + (size_t)i*256*HD, ew2p + (size_t)i*128*HD,
        eb1 + i*HD, eb2 + i*HD,
        ew1 + (size_t)i*258*HD + 256*HD, msg);
    agg_kernel<<<(NN + 3)/4, 256, 0, stream>>>((const unsigned int*)msg, off, (unsigned int*)aggb);
    node_kernel<<<(NN + 63)/64, 256, 0, stream>>>(hbuf, aggb,
        nw1p + (size_t)i*256*HD, nw2p + (size_t)i*128*HD,
        nb1 + i*HD, nb2 + i*HD, hf);
  }

  dec_kernel<<<(NN + 63)/64, 256, 0, stream>>>(hbuf, dw1p, db1, dw2, db2, (float*)d_out);
}

// Round 3
// 886.554 us; speedup vs baseline: 1.4957x; 1.1764x over previous
//
#include <hip/hip_runtime.h>

#define NN 50000
#define NE 600000
#define HD 128
#define NL 4

typedef __bf16 bf16x8 __attribute__((ext_vector_type(8)));
typedef float f32x4 __attribute__((ext_vector_type(4)));

__device__ __forceinline__ unsigned short f2bf(float x){
  union { float f; unsigned int u; } v; v.f = x;
  unsigned int r = v.u + 0x7FFFu + ((v.u >> 16) & 1u);
  return (unsigned short)(r >> 16);
}
__device__ __forceinline__ float bflo(unsigned u){ union{unsigned u; float f;} v; v.u = u << 16; return v.f; }
__device__ __forceinline__ float bfhi(unsigned u){ union{unsigned u; float f;} v; v.u = u & 0xffff0000u; return v.f; }

// silu via raw trans ops: avoids precise-div expansion (v_div_scale/fmas/fixup)
__device__ __forceinline__ float silu_f(float x){
  float e, r;
  float t = x * -1.44269504088896340736f;   // exp(-x) = 2^(-x*log2e)
  asm("v_exp_f32 %0, %1" : "=v"(e) : "v"(t));
  float d = 1.f + e;
  asm("v_rcp_f32 %0, %1" : "=v"(r) : "v"(d));
  return x * r;
}

__device__ __forceinline__ f32x4 mfma_b16(bf16x8 a, bf16x8 b, f32x4 c){
  return __builtin_amdgcn_mfma_f32_16x16x32_bf16(a, b, c, 0, 0, 0);
}

// pack weight [K x 128] f32 row-major -> MFMA B-fragment order (bf16); rows >= Klimit -> 0
__global__ __launch_bounds__(256) void pack_b(const float* __restrict__ src,
    unsigned short* __restrict__ dst, int K, int Klimit, int srcLayerStride){
  int layer = blockIdx.y;
  int tid = blockIdx.x*256 + threadIdx.x;           // < K*128
  int j = tid & 7, lane = (tid >> 3) & 63, nb = (tid >> 9) & 7, kk = tid >> 12;
  int krow = (kk << 5) + ((lane >> 4) << 3) + j;
  int c = (nb << 4) + (lane & 15);
  float v = (krow < Klimit) ? src[(size_t)layer*srcLayerStride + krow*HD + c] : 0.f;
  dst[(size_t)layer*K*HD + tid] = f2bf(v);
}

__global__ __launch_bounds__(256) void emb_kernel(
    const float* __restrict__ loc, const float* __restrict__ vel,
    const float* __restrict__ ew, const float* __restrict__ eb,
    float* __restrict__ hf, unsigned short* __restrict__ hb)
{
  int gid = blockIdx.x*256 + threadIdx.x;   // = n*128 + j
  int n = gid >> 7, j = gid & 127;
  float s = eb[j];
  s += loc[n*3+0]*ew[0*HD+j] + loc[n*3+1]*ew[1*HD+j] + loc[n*3+2]*ew[2*HD+j];
  s += vel[n*3+0]*ew[3*HD+j] + vel[n*3+1]*ew[4*HD+j] + vel[n*3+2]*ew[5*HD+j];
  hf[gid] = s;
  hb[gid] = f2bf(s);
}

// ---- CSR build ----
__global__ __launch_bounds__(256) void count_kernel(const int* __restrict__ rowIdx, int* __restrict__ cnt){
  int e = blockIdx.x*256 + threadIdx.x;
  if (e < NE) atomicAdd(cnt + rowIdx[e], 1);
}

__global__ __launch_bounds__(1024) void scan_kernel(const int* __restrict__ cnt,
    int* __restrict__ off, int* __restrict__ cur){
  __shared__ int part[1024];
  const int t = threadIdx.x;
  const int CH = (NN + 1023)/1024;
  const int base = t*CH;
  int s = 0;
  for (int i = 0; i < CH; ++i){
    int idx = base + i;
    if (idx < NN) s += cnt[idx];
  }
  part[t] = s;
  __syncthreads();
  for (int d = 1; d < 1024; d <<= 1){
    int v = (t >= d) ? part[t-d] : 0;
    __syncthreads();
    part[t] += v;
    __syncthreads();
  }
  int run = (t == 0) ? 0 : part[t-1];
  for (int i = 0; i < CH; ++i){
    int idx = base + i;
    if (idx < NN){
      off[idx] = run; cur[idx] = run;
      run += cnt[idx];
    }
  }
  if (t == 0) off[NN] = part[1023];
}

__global__ __launch_bounds__(256) void assign_kernel(
    const int* __restrict__ rowIdx, const int* __restrict__ colIdx,
    const float* __restrict__ ea, int* __restrict__ cur,
    int* __restrict__ row_s, int* __restrict__ col_s, float* __restrict__ ea_s){
  int e = blockIdx.x*256 + threadIdx.x;
  if (e < NE){
    int r = rowIdx[e];
    int s = atomicAdd(cur + r, 1);
    row_s[s] = r;
    col_s[s] = colIdx[e];
    ea_s[2*s]   = ea[2*e];
    ea_s[2*s+1] = ea[2*e+1];
  }
}

// ---- edge kernel (row-sorted, frag-major LDS, ea folded into GEMM1 K=288) ----
__global__ __launch_bounds__(256) void edge_kernel(
    const unsigned short* __restrict__ hb,
    const int* __restrict__ row_s, const int* __restrict__ col_s,
    const float* __restrict__ ea_s,
    const unsigned short* __restrict__ B1p, const unsigned short* __restrict__ B2p,
    const float* __restrict__ bias1, const float* __restrict__ bias2,
    unsigned short* __restrict__ msg)
{
  // frag-major: slot s = (kk*4 + rtile)*64 + lane, 16B per slot. 9 kk-blocks (K=288)
  __shared__ alignas(128) char sA[2304*16];   // 36 KB; sT (GEMM2 A, 16KB) aliases the front
  uint4* sA4 = reinterpret_cast<uint4*>(sA);

  const int t = threadIdx.x;
  const int e0 = blockIdx.x << 6;

  { // stage [h[row] | h[col]] : 4 threads/edge; each 16B chunk = one frag slot
    const int el = t >> 2, p = t & 3;
    const int node = (p < 2) ? row_s[e0 + el] : col_s[e0 + el];
    const uint4* src = reinterpret_cast<const uint4*>(hb + (size_t)node*HD + (p & 1)*64);
    const int base16 = (p << 9) + ((el >> 4) << 6) + (el & 15);
    #pragma unroll
    for (int c = 0; c < 8; ++c)
      sA4[base16 + ((c >> 2) << 8) + ((c & 3) << 4)] = src[c];
    if (p == 3){ // ea -> features 256-257 of kk-block 8 (rest zero)
      const int eb16 = 2048 + ((el >> 4) << 6) + (el & 15);
      uint4 z = make_uint4(0,0,0,0);
      uint4 d = z;
      d.x = (unsigned)f2bf(ea_s[2*(e0 + el)]) | ((unsigned)f2bf(ea_s[2*(e0 + el) + 1]) << 16);
      sA4[eb16]       = d;
      sA4[eb16 + 16]  = z;
      sA4[eb16 + 32]  = z;
      sA4[eb16 + 48]  = z;
    }
  }
  __syncthreads();

  const int w = t >> 6, l = t & 63;
  const int lw = l >> 4, ll = l & 15;

  f32x4 acc[4][2] = {};
  #pragma unroll
  for (int kk = 0; kk < 9; ++kk){
    bf16x8 a[4], b[2];
    #pragma unroll
    for (int r = 0; r < 4; ++r)
      a[r] = *reinterpret_cast<const bf16x8*>(&sA4[((kk << 2) + r)*64 + l]);
    #pragma unroll
    for (int c = 0; c < 2; ++c)
      b[c] = *reinterpret_cast<const bf16x8*>(B1p + ((((kk << 3) + (w << 1) + c) << 6) + l)*8);
    #pragma unroll
    for (int r = 0; r < 4; ++r)
      #pragma unroll
      for (int c = 0; c < 2; ++c)
        acc[r][c] = mfma_b16(a[r], b[c], acc[r][c]);
  }
  __syncthreads();   // sA reads done; sT aliases sA

  // epilogue 1: + bias + SiLU -> sT frag slots (A-operand of GEMM2)
  // value (rt=r*16+lw*4+i, col=w*32+c*16+ll) -> byte (w*4+r)*1024 + (lw*4+i)*16 + (c*2+(ll>>3))*256 + (ll&7)*2
  {
    const int ebase = (lw << 6) + ((ll >> 3) << 8) + ((ll & 7) << 1) + (w << 12);
    #pragma unroll
    for (int c = 0; c < 2; ++c){
      float b1 = bias1[(w << 5) + (c << 4) + ll];
      #pragma unroll
      for (int r = 0; r < 4; ++r){
        #pragma unroll
        for (int i = 0; i < 4; ++i){
          float v = silu_f(acc[r][c][i] + b1);
          *reinterpret_cast<unsigned short*>(sA + (ebase + (r << 10) + (i << 4) + (c << 9))) = f2bf(v);
        }
      }
    }
  }
  __syncthreads();

  f32x4 acc2[4][2] = {};
  #pragma unroll
  for (int kk = 0; kk < 4; ++kk){
    bf16x8 a[4], b[2];
    #pragma unroll
    for (int r = 0; r < 4; ++r)
      a[r] = *reinterpret_cast<const bf16x8*>(&sA4[((kk << 2) + r)*64 + l]);
    #pragma unroll
    for (int c = 0; c < 2; ++c)
      b[c] = *reinterpret_cast<const bf16x8*>(B2p + ((((kk << 3) + (w << 1) + c) << 6) + l)*8);
    #pragma unroll
    for (int r = 0; r < 4; ++r)
      #pragma unroll
      for (int c = 0; c < 2; ++c)
        acc2[r][c] = mfma_b16(a[r], b[c], acc2[r][c]);
  }
  __syncthreads();   // sT reads done before rewrite

  // epilogue 2: + bias + SiLU -> sT frag slots, then coalesced copy-out
  {
    const int ebase = (lw << 6) + ((ll >> 3) << 8) + ((ll & 7) << 1) + (w << 12);
    #pragma unroll
    for (int c = 0; c < 2; ++c){
      float b2 = bias2[(w << 5) + (c << 4) + ll];
      #pragma unroll
      for (int r = 0; r < 4; ++r){
        #pragma unroll
        for (int i = 0; i < 4; ++i){
          float v = silu_f(acc2[r][c][i] + b2);
          *reinterpret_cast<unsigned short*>(sA + (ebase + (r << 10) + (i << 4) + (c << 9))) = f2bf(v);
        }
      }
    }
  }
  __syncthreads();

  { // copy out: thread t -> edge e=(t>>4)+it*16, 16B chunk q=t&15
    uint4* dst = reinterpret_cast<uint4*>(msg + (size_t)e0*HD);
    const int q = t & 15;
    #pragma unroll
    for (int it = 0; it < 4; ++it){
      int e = (t >> 4) + (it << 4);
      int src16 = (((q >> 2) << 2) + (e >> 4))*64 + (e & 15) + ((q & 3) << 4);
      dst[(e << 4) + q] = sA4[src16];
    }
  }
}

// ---- aggregation: aggb[n] = sum of msg rows in [off[n], off[n+1]) ----
__global__ __launch_bounds__(256) void agg_kernel(
    const unsigned int* __restrict__ msg32, const int* __restrict__ off,
    unsigned int* __restrict__ aggb32)
{
  const int t = threadIdx.x;
  const int w = t >> 6, lane = t & 63;
  const int n = (blockIdx.x << 2) + w;
  if (n >= NN) return;
  const int j0 = off[n], j1 = off[n+1];
  float a0 = 0.f, a1 = 0.f;
  int j = j0;
  for (; j + 1 < j1; j += 2){
    unsigned u0 = msg32[(size_t)j*64 + lane];
    unsigned u1 = msg32[(size_t)(j+1)*64 + lane];
    a0 += bflo(u0) + bflo(u1);
    a1 += bfhi(u0) + bfhi(u1);
  }
  if (j < j1){
    unsigned u0 = msg32[(size_t)j*64 + lane];
    a0 += bflo(u0);
    a1 += bfhi(u0);
  }
  aggb32[(size_t)n*64 + lane] = (unsigned)f2bf(a0) | ((unsigned)f2bf(a1) << 16);
}

// ---- node kernel (frag-major): h += silu([h|agg] @ W1 + b1) @ W2 + b2 ----
__global__ __launch_bounds__(256) void node_kernel(
    unsigned short* hb, const unsigned short* __restrict__ aggb,
    const unsigned short* __restrict__ B1p, const unsigned short* __restrict__ B2p,
    const float* __restrict__ bias1, const float* __restrict__ bias2,
    float* hf)
{
  __shared__ alignas(128) char sA[2048*16];   // 32 KB, 8 kk-blocks; sT aliases front
  uint4* sA4 = reinterpret_cast<uint4*>(sA);
  const int t = threadIdx.x;
  const int n0 = blockIdx.x << 6;

  {
    const int nl_ = t >> 2, p = t & 3;
    const int n = n0 + nl_;
    const bool valid = (n < NN);
    const int nc = valid ? n : 0;
    const unsigned short* basep = (p < 2) ? hb : aggb;
    const uint4* src = reinterpret_cast<const uint4*>(basep + (size_t)nc*HD + (p & 1)*64);
    const int base16 = (p << 9) + ((nl_ >> 4) << 6) + (nl_ & 15);
    #pragma unroll
    for (int c = 0; c < 8; ++c){
      uint4 d = valid ? src[c] : make_uint4(0,0,0,0);
      sA4[base16 + ((c >> 2) << 8) + ((c & 3) << 4)] = d;
    }
  }
  __syncthreads();

  const int w = t >> 6, l = t & 63;
  const int lw = l >> 4, ll = l & 15;

  f32x4 acc[4][2] = {};
  #pragma unroll
  for (int kk = 0; kk < 8; ++kk){
    bf16x8 a[4], b[2];
    #pragma unroll
    for (int r = 0; r < 4; ++r)
      a[r] = *reinterpret_cast<const bf16x8*>(&sA4[((kk << 2) + r)*64 + l]);
    #pragma unroll
    for (int c = 0; c < 2; ++c)
      b[c] = *reinterpret_cast<const bf16x8*>(B1p + ((((kk << 3) + (w << 1) + c) << 6) + l)*8);
    #pragma unroll
    for (int r = 0; r < 4; ++r)
      #pragma unroll
      for (int c = 0; c < 2; ++c)
        acc[r][c] = mfma_b16(a[r], b[c], acc[r][c]);
  }
  __syncthreads();

  {
    const int ebase = (lw << 6) + ((ll >> 3) << 8) + ((ll & 7) << 1) + (w << 12);
    #pragma unroll
    for (int c = 0; c < 2; ++c){
      float b1 = bias1[(w << 5) + (c << 4) + ll];
      #pragma unroll
      for (int r = 0; r < 4; ++r){
        #pragma unroll
        for (int i = 0; i < 4; ++i){
          float v = silu_f(acc[r][c][i] + b1);
          *reinterpret_cast<unsigned short*>(sA + (ebase + (r << 10) + (i << 4) + (c << 9))) = f2bf(v);
        }
      }
    }
  }
  __syncthreads();

  f32x4 acc2[4][2] = {};
  #pragma unroll
  for (int kk = 0; kk < 4; ++kk){
    bf16x8 a[4], b[2];
    #pragma unroll
    for (int r = 0; r < 4; ++r)
      a[r] = *reinterpret_cast<const bf16x8*>(&sA4[((kk << 2) + r)*64 + l]);
    #pragma unroll
    for (int c = 0; c < 2; ++c)
      b[c] = *reinterpret_cast<const bf16x8*>(B2p + ((((kk << 3) + (w << 1) + c) << 6) + l)*8);
    #pragma unroll
    for (int r = 0; r < 4; ++r)
      #pragma unroll
      for (int c = 0; c < 2; ++c)
        acc2[r][c] = mfma_b16(a[r], b[c], acc2[r][c]);
  }

  #pragma unroll
  for (int r = 0; r < 4; ++r){
    #pragma unroll
    for (int i = 0; i < 4; ++i){
      int rt = (r << 4) + (lw << 2) + i;
      int n = n0 + rt;
      if (n < NN){
        #pragma unroll
        for (int c = 0; c < 2; ++c){
          int col = (w << 5) + (c << 4) + ll;
          float hn = hf[(size_t)n*HD + col] + acc2[r][c][i] + bias2[col];
          hf[(size_t)n*HD + col] = hn;
          hb[(size_t)n*HD + col] = f2bf(hn);
        }
      }
    }
  }
}

// ---- decoder: out = silu(h @ dw1 + db1) @ dw2 + db2 ----
__global__ __launch_bounds__(256) void dec_kernel(
    const unsigned short* __restrict__ hb, const unsigned short* __restrict__ D1p,
    const float* __restrict__ db1, const float* __restrict__ dw2,
    const float* __restrict__ db2, float* __restrict__ outp)
{
  __shared__ alignas(128) char sA[1024*16];   // 16KB frag-major
  uint4* sA4 = reinterpret_cast<uint4*>(sA);
  __shared__ float sT[64*133];
  const int t = threadIdx.x;
  const int n0 = blockIdx.x << 6;
  {
    const int nl_ = t >> 2, p = t & 3;    // p = 16B chunk group (feats p*32..)
    const int n = n0 + nl_;
    const bool valid = (n < NN);
    const int nc = valid ? n : 0;
    const uint4* src = reinterpret_cast<const uint4*>(hb + (size_t)nc*HD);
    const int base16 = ((nl_ >> 4) << 6) + (nl_ & 15);
    #pragma unroll
    for (int c = 0; c < 4; ++c){            // chunk index q = p*4+c, f0=q*8
      int q = (p << 2) + c;
      uint4 d = valid ? src[q] : make_uint4(0,0,0,0);
      sA4[base16 + ((q >> 2) << 8) + ((q & 3) << 4)] = d;
    }
  }
  __syncthreads();

  const int w = t >> 6, l = t & 63;
  const int lw = l >> 4, ll = l & 15;

  f32x4 acc[4][2] = {};
  #pragma unroll
  for (int kk = 0; kk < 4; ++kk){
    bf16x8 a[4], b[2];
    #pragma unroll
    for (int r = 0; r < 4; ++r)
      a[r] = *reinterpret_cast<const bf16x8*>(&sA4[((kk << 2) + r)*64 + l]);
    #pragma unroll
    for (int c = 0; c < 2; ++c)
      b[c] = *reinterpret_cast<const bf16x8*>(D1p + ((((kk << 3) + (w << 1) + c) << 6) + l)*8);
    #pragma unroll
    for (int r = 0; r < 4; ++r)
      #pragma unroll
      for (int c = 0; c < 2; ++c)
        acc[r][c] = mfma_b16(a[r], b[c], acc[r][c]);
  }
  #pragma unroll
  for (int r = 0; r < 4; ++r){
    #pragma unroll
    for (int i = 0; i < 4; ++i){
      int rt = (r << 4) + (lw << 2) + i;
      #pragma unroll
      for (int c = 0; c < 2; ++c){
        int col = (w << 5) + (c << 4) + ll;
        sT[rt*133 + col] = silu_f(acc[r][c][i] + db1[col]);
      }
    }
  }
  __syncthreads();
  if (t < 192){
    int rr = t & 63, cc = t >> 6;
    int n = n0 + rr;
    if (n < NN){
      float s = db2[cc];
      #pragma unroll 8
      for (int k = 0; k < HD; ++k) s += sT[rr*133 + k]*dw2[k*3 + cc];
      outp[(size_t)n*3 + cc] = s;
    }
  }
}

static inline char* alignup(char* p, size_t a){ return (char*)(((uintptr_t)p + a - 1) & ~(a - 1)); }

extern "C" void kernel_launch(void* const* d_in, const int* in_sizes, int n_in,
                              void* d_out, int out_size, void* d_ws, size_t ws_size,
                              hipStream_t stream)
{
  const float* loc  = (const float*)d_in[0];
  const float* vel  = (const float*)d_in[1];
  const float* ea   = (const float*)d_in[2];
  const int*   row  = (const int*)d_in[3];
  const int*   col  = (const int*)d_in[4];
  const float* embw = (const float*)d_in[5];
  const float* embb = (const float*)d_in[6];
  const float* ew1  = (const float*)d_in[7];
  const float* eb1  = (const float*)d_in[8];
  const float* ew2  = (const float*)d_in[9];
  const float* eb2  = (const float*)d_in[10];
  const float* nw1  = (const float*)d_in[11];
  const float* nb1  = (const float*)d_in[12];
  const float* nw2  = (const float*)d_in[13];
  const float* nb2  = (const float*)d_in[14];
  const float* dw1  = (const float*)d_in[15];
  const float* db1  = (const float*)d_in[16];
  const float* dw2  = (const float*)d_in[17];
  const float* db2  = (const float*)d_in[18];

  char* p = (char*)d_ws;
  float* hf = (float*)p;                       p += (size_t)NN*HD*4;
  unsigned short* hbuf = (unsigned short*)p;   p += (size_t)NN*HD*2;
  unsigned short* aggb = (unsigned short*)p;   p += (size_t)NN*HD*2;
  unsigned short* msg = (unsigned short*)p;    p += (size_t)NE*HD*2;
  int* cnt = (int*)p;                          p += (size_t)NN*4;
  int* off = (int*)p;                          p += (size_t)(NN+1)*4;   p = alignup(p, 256);
  int* cur = (int*)p;                          p += (size_t)NN*4;
  int* row_s = (int*)p;                        p += (size_t)NE*4;
  int* col_s = (int*)p;                        p += (size_t)NE*4;
  float* ea_s = (float*)p;                     p += (size_t)NE*2*4;
  unsigned short* ew1p = (unsigned short*)p;   p += (size_t)NL*288*HD*2;
  unsigned short* ew2p = (unsigned short*)p;   p += (size_t)NL*128*HD*2;
  unsigned short* nw1p = (unsigned short*)p;   p += (size_t)NL*256*HD*2;
  unsigned short* nw2p = (unsigned short*)p;   p += (size_t)NL*128*HD*2;
  unsigned short* dw1p = (unsigned short*)p;   p += (size_t)128*HD*2;

  // CSR build (once; row/col/ea don't change across layers)
  hipMemsetAsync(cnt, 0, (size_t)NN*4, stream);
  count_kernel<<<(NE + 255)/256, 256, 0, stream>>>(row, cnt);
  scan_kernel<<<1, 1024, 0, stream>>>(cnt, off, cur);
  assign_kernel<<<(NE + 255)/256, 256, 0, stream>>>(row, col, ea, cur, row_s, col_s, ea_s);

  pack_b<<<dim3(144, NL), 256, 0, stream>>>(ew1, ew1p, 288, 258, 258*HD);
  pack_b<<<dim3(64,  NL), 256, 0, stream>>>(ew2, ew2p, 128, 128, 128*HD);
  pack_b<<<dim3(128, NL), 256, 0, stream>>>(nw1, nw1p, 256, 256, 256*HD);
  pack_b<<<dim3(64,  NL), 256, 0, stream>>>(nw2, nw2p, 128, 128, 128*HD);
  pack_b<<<dim3(64,  1 ), 256, 0, stream>>>(dw1, dw1p, 128, 128, 0);

  emb_kernel<<<(NN*HD)/256, 256, 0, stream>>>(loc, vel, embw, embb, hf, hbuf);

  for (int i = 0; i < NL; ++i){
    edge_kernel<<<NE/64, 256, 0, stream>>>(hbuf, row_s, col_s, ea_s,
        ew1p + (size_t)i*288*HD, ew2p + (size_t)i*128*HD,
        eb1 + i*HD, eb2 + i*HD, msg);
    agg_kernel<<<(NN + 3)/4, 256, 0, stream>>>((const unsigned int*)msg, off, (unsigned int*)aggb);
    node_kernel<<<(NN + 63)/64, 256, 0, stream>>>(hbuf, aggb,
        nw1p + (size_t)i*256*HD, nw2p + (size_t)i*128*HD,
        nb1 + i*HD, nb2 + i*HD, hf);
  }

  dec_kernel<<<(NN + 63)/64, 256, 0, stream>>>(hbuf, dw1p, db1, dw2, db2, (float*)d_out);
}